// Round 15
// baseline (315.304 us; speedup 1.0000x reference)
//
#include <hip/hip_runtime.h>
#include <stdint.h>

#define S_LEN 2048
#define HEADS 16
#define DIM   64
// bh = b*HEADS + h, BH = 32.

typedef float  f4v  __attribute__((ext_vector_type(4)));
typedef float  f2v  __attribute__((ext_vector_type(2)));
typedef float  f16v __attribute__((ext_vector_type(16)));
typedef short  s8v  __attribute__((ext_vector_type(8)));
typedef unsigned int   u4v  __attribute__((ext_vector_type(4)));
typedef unsigned short us4v __attribute__((ext_vector_type(4)));

#define LOGC 0.105360516f   // ln(1/0.9): folds the 1/(1-p) dropout scale into exp

__device__ __forceinline__ unsigned short f2bf(float f) {
  unsigned int u = __float_as_uint(f);
  u += 0x7fffu + ((u >> 16) & 1u);   // round-to-nearest-even
  return (unsigned short)(u >> 16);
}
__device__ __forceinline__ float bf2f(unsigned short h) {
  return __uint_as_float(((unsigned int)h) << 16);
}
__device__ __forceinline__ unsigned int pk2(float e0, float e1) {
  return (unsigned int)f2bf(e0) | ((unsigned int)f2bf(e1) << 16);
}

// ---- fused prep: K -> fragment-ordered bf16 hi/lo ; V -> fragment-ordered bf16
// blocks [0,2048): K path. blocks [2048,4096): V path.
// Khf/Klf flat: [bh][kt][dc][lane][j=8] ; value = K(s=kt*32+(l&31), d=dc*16+(l>>5)*8+j)
// Vf flat: [bh][kt][kc*2+dblk][lane][j=8] ; value = V(s=kt*32+kc*16+(l>>5)*8+j, d=dblk*32+(l&31))
__global__ __launch_bounds__(256) void prep_kv(const float* __restrict__ K,
                                               const float* __restrict__ V,
                                               unsigned short* __restrict__ Khf,
                                               unsigned short* __restrict__ Klf,
                                               unsigned short* __restrict__ Vf) {
  __shared__ float tile[32 * 68];                  // V path staging, pitch 68
  if (blockIdx.x < 2048) {
    int f = blockIdx.x * 256 + threadIdx.x;        // 524288 threads
    int l  = f & 63;
    int dc = (f >> 6) & 3;
    int kt = (f >> 8) & 63;
    int bh = f >> 14;
    int b = bh >> 4, hh = bh & 15;
    int s  = kt * 32 + (l & 31);
    int d0 = dc * 16 + (l >> 5) * 8;
    const float* src = K + (((size_t)(b * S_LEN + s) * HEADS + hh) << 6) + d0;
    f4v va = *(const f4v*)src;
    f4v vb = *(const f4v*)(src + 4);
    us4v ha, hb, la, lb;
#pragma unroll
    for (int i = 0; i < 4; ++i) {
      unsigned short h = f2bf(va[i]);
      ha[i] = h; la[i] = f2bf(va[i] - bf2f(h));
      unsigned short h2 = f2bf(vb[i]);
      hb[i] = h2; lb[i] = f2bf(vb[i] - bf2f(h2));
    }
    size_t o = (size_t)f * 8;
    *(us4v*)(Khf + o) = ha; *(us4v*)(Khf + o + 4) = hb;
    *(us4v*)(Klf + o) = la; *(us4v*)(Klf + o + 4) = lb;
  } else {
    int bid = blockIdx.x - 2048;
    int bh = bid >> 6;
    int kt = bid & 63;
    int b = bh >> 4, hh = bh & 15;
    int t = threadIdx.x;
    {
      int row = t >> 3, c8 = (t & 7) * 8;
      const float* src =
          V + (((size_t)(b * S_LEN + kt * 32 + row) * HEADS + hh) << 6) + c8;
      f4v va = *(const f4v*)src;
      f4v vb = *(const f4v*)(src + 4);
      *(f4v*)(tile + row * 68 + c8) = va;
      *(f4v*)(tile + row * 68 + c8 + 4) = vb;
    }
    __syncthreads();
    int kc = t >> 7, dblk = (t >> 6) & 1, l = t & 63;
    int s0 = kc * 16 + (l >> 5) * 8;
    int col = dblk * 32 + (l & 31);
    us4v w0, w1;
#pragma unroll
    for (int j = 0; j < 4; ++j) {
      w0[j] = f2bf(tile[(s0 + j) * 68 + col]);
      w1[j] = f2bf(tile[(s0 + 4 + j) * 68 + col]);
    }
    size_t o = ((((size_t)bh * 64 + kt) * 4 + kc * 2 + dblk) * 64 + l) * 8;
    *(us4v*)(Vf + o) = w0;
    *(us4v*)(Vf + o + 4) = w1;
  }
}

// ---- main: flash attention, in-block kv-split. 512 threads = 8 waves: waves
// 0-3 sweep kv[0,1024), waves 4-7 kv[1024,2048) for the SAME 128 q rows; the
// flash-merge happens in-block via LDS (no Opart/ML workspace, no combine
// kernel). Loop body identical to the round-10 champion: QK in C-layout
// (coalesced mask/u, computed addressing), f32 scores transposed through
// wave-private LDS (drop-flag in mantissa LSB), softmax lane-local.
// NOTE: (256,4)-style tight bounds spill GB/pass (round 5); register prefetch
// of mask/u spills in ANY form (rounds 8/9); (256,3) exposes latency (round
// 11); explicit vmcnt/setprio pipelining regresses (round 13); hoisting the
// u-stream to a serial prep pass de-overlaps it (round 14). Plain loads, 2
// waves/SIMD.
__global__ __launch_bounds__(512, 2) void attn_fwd(
    const float* __restrict__ Q, const float* __restrict__ MASK,
    const float* __restrict__ U, const unsigned short* __restrict__ Khf,
    const unsigned short* __restrict__ Klf, const unsigned short* __restrict__ Vf,
    float* __restrict__ OUT) {
  __shared__ float S_lds[8][1024];                 // per-wave 32x32 f32 scores
  __shared__ float MLx[4][32][2];                  // (m,l) exchange, sp=1 -> sp=0
  int bid = blockIdx.x;
  int lid = ((bid & 7) << 6) + (bid >> 3);         // XCD-bijective swizzle (512)
  int bh = lid >> 4, qt = lid & 15;
  int wv = threadIdx.x >> 6, ln = threadIdx.x & 63;
  int wq = wv & 3, sp = wv >> 2;
  int l31 = ln & 31, h5 = ln >> 5;
  int q0 = qt * 128 + wq * 32;
  int b = bh >> 4, hh = bh & 15;
  const int kv_begin = sp * (S_LEN / 2);
  const int NT = S_LEN / 64;                       // 32 tiles per wave
  float* lds = &S_lds[wv][0];

  // Q A-fragments (hi/lo): lane l -> row q0+l31, d = dc*16 + 8*h5 + j
  const float* qrow = Q + (((size_t)(b * S_LEN + q0 + l31) * HEADS + hh) << 6);
  s8v qfh[4], qfl[4];
#pragma unroll
  for (int dc = 0; dc < 4; ++dc) {
    const float* p = qrow + dc * 16 + 8 * h5;
    f4v va = *(const f4v*)p;
    f4v vb = *(const f4v*)(p + 4);
    u4v wh, wl;
#pragma unroll
    for (int t = 0; t < 4; ++t) {
      float x0 = (t < 2) ? va[2 * t] : vb[2 * (t - 2)];
      float x1 = (t < 2) ? va[2 * t + 1] : vb[2 * (t - 2) + 1];
      unsigned short h0 = f2bf(x0), h1 = f2bf(x1);
      wh[t] = (unsigned)h0 | ((unsigned)h1 << 16);
      wl[t] = pk2(x0 - bf2f(h0), x1 - bf2f(h1));
    }
    qfh[dc] = __builtin_bit_cast(s8v, wh);
    qfl[dc] = __builtin_bit_cast(s8v, wl);
  }

  // mask/u: computed addressing — single lane-varying base index + per-row
  // compile-time constants (fold to SGPR/imm, no VGPR table)
  const float* Mp = MASK + ((size_t)bh << 22);
  const float* Up = U + ((size_t)bh << 22);
  const int vbase = (q0 + 4 * h5) * S_LEN + kv_begin + l31;

  const unsigned short* kbh = Khf + ((size_t)bh << 17) + ((size_t)kv_begin << 6);
  const unsigned short* kbl = Klf + ((size_t)bh << 17) + ((size_t)kv_begin << 6);
  const unsigned short* vbp = Vf + ((size_t)bh << 17) + ((size_t)kv_begin << 6);
  const int fl8 = ln * 8;

  f16v o0, o1;
#pragma unroll
  for (int i = 0; i < 16; ++i) { o0[i] = 0.f; o1[i] = 0.f; }
  float mrs = -3.0e38f;   // running row max, pre-shifted by -LOGC (lane = row l31)
  float pl  = 0.f;        // undropped sum of P/0.9 for this lane's k-half

  for (int kt = 0; kt < NT; ++kt) {
    int kv0 = kt << 5;
    // K B-fragments (coalesced 1KB loads, L2-resident)
    s8v kfh[4], kfl[4];
#pragma unroll
    for (int dc = 0; dc < 4; ++dc) {
      size_t off = (size_t)((kt * 4 + dc) << 9) + fl8;
      kfh[dc] = *(const s8v*)(kbh + off);
      kfl[dc] = *(const s8v*)(kbl + off);
    }
    // V B-fragments (coalesced 1KB loads, L2-resident)
    s8v vf[2][2];
#pragma unroll
    for (int kc = 0; kc < 2; ++kc)
#pragma unroll
      for (int db = 0; db < 2; ++db)
        vf[kc][db] = *(const s8v*)(vbp + (size_t)((kt * 4 + kc * 2 + db) << 9) + fl8);
    // mask / u in C-layout: reg r -> row q0+8*(r>>2)+4*h5+(r&3), col kv0+l31
    float mk[16], uk[16];
#pragma unroll
    for (int r = 0; r < 16; ++r) {
      int off = vbase + kv0 + (8 * (r >> 2) + (r & 3)) * S_LEN;
      mk[r] = Mp[off];
      uk[r] = Up[off];
    }
    // S = Q·K^T (fp32-accurate via hi/lo split)
    f16v sc;
#pragma unroll
    for (int i = 0; i < 16; ++i) sc[i] = 0.f;
#pragma unroll
    for (int dc = 0; dc < 4; ++dc) {
      sc = __builtin_amdgcn_mfma_f32_32x32x16_bf16(qfh[dc], kfh[dc], sc, 0, 0, 0);
      sc = __builtin_amdgcn_mfma_f32_32x32x16_bf16(qfl[dc], kfh[dc], sc, 0, 0, 0);
      sc = __builtin_amdgcn_mfma_f32_32x32x16_bf16(qfh[dc], kfl[dc], sc, 0, 0, 0);
    }
    // phase A: sv = 8*sc + mask, drop-flag -> mantissa LSB, write f32 [q][k]
    // swizzled: word = qr*32 + ((l31>>2 ^ qr&7)<<2 | l31&3)   (2-way on write)
#pragma unroll
    for (int r = 0; r < 16; ++r) {
      float sv = fmaf(sc[r], 8.0f, mk[r]);
      unsigned bits = (__float_as_uint(sv) & ~1u) | (uk[r] < 0.1f ? 1u : 0u);
      int qr = 8 * (r >> 2) + 4 * h5 + (r & 3);
      lds[qr * 32 + (((((l31 >> 2) ^ (qr & 7)) << 2)) | (l31 & 3))] =
          __uint_as_float(bits);
    }
    __builtin_amdgcn_sched_barrier(0);             // keep reads after writes
    // phase B: transposed read — lane owns row l31; h5 picks k-chunks
    f4v sq[4];
#pragma unroll
    for (int cc = 0; cc < 4; ++cc) {
      int c = (cc >> 1) * 4 + (cc & 1) + 2 * h5;
      sq[cc] = *(const f4v*)(lds + l31 * 32 + ((c ^ (l31 & 7)) << 2));
    }
    // lane-local row max (15 fmax) + pair across k-halves (1 shfl)
    float tm = -3.0e38f;
#pragma unroll
    for (int cc = 0; cc < 4; ++cc)
#pragma unroll
      for (int w = 0; w < 4; ++w) tm = fmaxf(tm, sq[cc][w]);
    float tmax = fmaxf(tm, __shfl_xor(tm, 32));
    // defer-max (THR=8), wave-uniform trigger
    if (__any(tmax > mrs + (8.0f + LOGC))) {
      float mold = mrs + LOGC;
      float mn = fmaxf(mold, tmax);
      float al = __expf(mold - mn);
      mrs = mn - LOGC;
      pl *= al;
#pragma unroll
      for (int r = 0; r < 16; ++r) {
        float arow = __shfl(al, 8 * (r >> 2) + 4 * h5 + (r & 3));
        o0[r] *= arow; o1[r] *= arow;
      }
    }
    // P' = exp(sv - mrs) = e^{sv-mrun}/0.9 ; pl += P' (undropped); drop -> pack
    u4v pa0, pa1;
#pragma unroll
    for (int cc = 0; cc < 4; ++cc) {
      float p0 = __expf(sq[cc][0] - mrs), p1 = __expf(sq[cc][1] - mrs);
      float p2 = __expf(sq[cc][2] - mrs), p3 = __expf(sq[cc][3] - mrs);
      pl += (p0 + p1) + (p2 + p3);
      float d0 = (__float_as_uint(sq[cc][0]) & 1u) ? 0.f : p0;
      float d1 = (__float_as_uint(sq[cc][1]) & 1u) ? 0.f : p1;
      float d2 = (__float_as_uint(sq[cc][2]) & 1u) ? 0.f : p2;
      float d3 = (__float_as_uint(sq[cc][3]) & 1u) ? 0.f : p3;
      unsigned w0 = pk2(d0, d1), w1 = pk2(d2, d3);
      if (cc < 2) { pa0[2 * cc] = w0; pa0[2 * cc + 1] = w1; }
      else        { pa1[2 * (cc - 2)] = w0; pa1[2 * (cc - 2) + 1] = w1; }
    }
    s8v paA = __builtin_bit_cast(s8v, pa0), paB = __builtin_bit_cast(s8v, pa1);
    // O += P·V
    o0 = __builtin_amdgcn_mfma_f32_32x32x16_bf16(paA, vf[0][0], o0, 0, 0, 0);
    o0 = __builtin_amdgcn_mfma_f32_32x32x16_bf16(paB, vf[1][0], o0, 0, 0, 0);
    o1 = __builtin_amdgcn_mfma_f32_32x32x16_bf16(paA, vf[0][1], o1, 0, 0, 0);
    o1 = __builtin_amdgcn_mfma_f32_32x32x16_bf16(paB, vf[1][1], o1, 0, 0, 0);
  }

  // combine k-halves within each wave (lanes R and R+32 hold the two halves)
  pl += __shfl_xor(pl, 32);

  // in-block flash-merge: sp=1 waves deposit (O, m, l); sp=0 waves merge.
  // Exchange region reuses S_lds (all loop use is complete after the barrier).
  float* xb = &S_lds[0][0] + wq * 2048;
  __syncthreads();
  if (sp) {
#pragma unroll
    for (int r = 0; r < 16; ++r) {
      xb[r * 64 + ln] = o0[r];
      xb[1024 + r * 64 + ln] = o1[r];
    }
    if (h5 == 0) { MLx[wq][l31][0] = mrs; MLx[wq][l31][1] = pl; }
  }
  __syncthreads();
  if (!sp) {
    float m1 = MLx[wq][l31][0], l1 = MLx[wq][l31][1];
    float M = fmaxf(mrs, m1);
    float a = __expf(mrs - M), bw = __expf(m1 - M);
    float inv = 1.0f / (0.9f * (pl * a + l1 * bw));
    float A = a * inv, B = bw * inv;
#pragma unroll
    for (int r = 0; r < 16; ++r) {
      int qr = 8 * (r >> 2) + 4 * h5 + (r & 3);
      float Ar = __shfl(A, qr), Br = __shfl(B, qr);
      float* orow = OUT + (((size_t)bh * S_LEN + q0 + qr) << 6) + l31;
      orow[0]  = o0[r] * Ar + xb[r * 64 + ln] * Br;
      orow[32] = o1[r] * Ar + xb[1024 + r * 64 + ln] * Br;
    }
  }
}

extern "C" void kernel_launch(void* const* d_in, const int* in_sizes, int n_in,
                              void* d_out, int out_size, void* d_ws, size_t ws_size,
                              hipStream_t stream) {
  const float* Q = (const float*)d_in[0];
  const float* K = (const float*)d_in[1];
  const float* V = (const float*)d_in[2];
  const float* M = (const float*)d_in[3];
  const float* U = (const float*)d_in[4];
  float* out = (float*)d_out;

  unsigned short* Khf = (unsigned short*)d_ws;              // 8 MB
  unsigned short* Klf = Khf + (size_t)(4u << 20);           // 8 MB
  unsigned short* Vf  = Klf + (size_t)(4u << 20);           // 8 MB (total 24 MB)

  prep_kv<<<4096, 256, 0, stream>>>(K, V, Khf, Klf, Vf);
  attn_fwd<<<512, 512, 0, stream>>>(Q, M, U, Khf, Klf, Vf, out);
}